// Round 2
// baseline (1640.157 us; speedup 1.0000x reference)
//
#include <hip/hip_runtime.h>
#include <cmath>

#ifndef M_PI
#define M_PI 3.14159265358979323846
#endif

// Problem dims
#define NB      2
#define N_PIX   147456          // 384*384
#define L_LEN   147456
#define TENS_SZ ((long)NB * 64 * N_PIX)   // 18,874,368 floats = 75,497,472 B per 64-plane tensor

// small-region float offsets (at d_ws + 3*TENS_SZ floats)
#define OFF_C    0      // C[a*8+m]
#define OFF_CI   64     // Ci[m*8+a]
#define OFF_LAM  128
#define OFF_GRAM 256    // [8][16][16]
#define OFF_QQ   2304   // [8][16]
#define OFF_KK   2432   // [8][16]
#define OFF_ATTN 2560   // [8][16][16]

// ---------------------------------------------------------------- init consts
__global__ __launch_bounds__(64) void init_k(const float* __restrict__ lq1, const float* __restrict__ lk1,
                                             const float* __restrict__ lq2, const float* __restrict__ lk2,
                                             float* __restrict__ sm) {
  int t = threadIdx.x;              // 64 threads
  int a = t >> 3, m = t & 7;
  double cv = 2.0 * cos(M_PI * (double)((2 * m + 1) * a) / 16.0);
  sm[OFF_C + a * 8 + m] = (float)cv;
  // inv(C) = C^T * diag(32,16,...,16)^-1
  sm[OFF_CI + m * 8 + a] = (float)(cv / ((a == 0) ? 32.0 : 16.0));
  float p1 = lq1[t] * lk1[t];
  float p2 = lq2[t] * lk2[t];
  #pragma unroll
  for (int off = 32; off; off >>= 1) {
    p1 += __shfl_xor(p1, off, 64);
    p2 += __shfl_xor(p2, off, 64);
  }
  if (t == 0) sm[OFF_LAM] = expf(p1) - expf(p2) + 0.70082066706704813f;
  for (int i = t; i < 2304; i += 64) sm[OFF_GRAM + i] = 0.f;
}

// ---------------------------------------------------------------- sentinel (ws too small)
__global__ void diag_k(float* out, float v) { out[0] = v; }

// ---------------------------------------------------------------- conv1x1: 64 -> 64 channels
// out[b, co, p] = sum_ci w[co*64+ci] * in[b, ci, p]
__global__ __launch_bounds__(256) void conv1x1_k(const float* __restrict__ in, const float* __restrict__ w,
                                                 float* __restrict__ out) {
  __shared__ float wl[4096];        // wl[ci*64+co]
  for (int i = threadIdx.x; i < 4096; i += 256) {
    int ci = i >> 6, co = i & 63;
    wl[i] = w[co * 64 + ci];
  }
  __syncthreads();
  long g = (long)blockIdx.x * 256 + threadIdx.x;   // [0, NB*N_PIX)
  int bb = (int)(g / N_PIX);
  int p  = (int)(g - (long)bb * N_PIX);
  const float* ip = in + (long)bb * 64 * N_PIX + p;
  float acc[64];
  #pragma unroll
  for (int co = 0; co < 64; co++) acc[co] = 0.f;
  for (int ci = 0; ci < 64; ci++) {
    float v = ip[(long)ci * N_PIX];
    #pragma unroll
    for (int co = 0; co < 64; co++) acc[co] = fmaf(wl[(ci << 6) + co], v, acc[co]);
  }
  float* op = out + (long)bb * 64 * N_PIX + p;
  #pragma unroll
  for (int co = 0; co < 64; co++) op[(long)co * N_PIX] = acc[co];
}

// ---------------------------------------------------------------- depthwise 3x3 (SAME, zero pad, cross-correlation)
__global__ __launch_bounds__(256) void dw3_k(const float* __restrict__ in, const float* __restrict__ w,
                                             float* __restrict__ out) {
  int x = blockIdx.x * 64 + threadIdx.x;
  int y = blockIdx.y * 4 + threadIdx.y;
  int plane = blockIdx.z;           // bb*64 + ch
  int ch = plane & 63;
  const float* ip = in + (long)plane * N_PIX;
  const float* wp = w + ch * 9;
  float s = 0.f;
  #pragma unroll
  for (int dy = 0; dy < 3; dy++) {
    int yy = y + dy - 1;
    if ((unsigned)yy >= 384u) continue;
    #pragma unroll
    for (int dx = 0; dx < 3; dx++) {
      int xx = x + dx - 1;
      if ((unsigned)xx >= 384u) continue;
      s = fmaf(wp[dy * 3 + dx], ip[yy * 384 + xx], s);
    }
  }
  out[(long)plane * N_PIX + y * 384 + x] = s;
}

// ---------------------------------------------------------------- DCT: spatial -> patch-flattened (b,64,L)
__global__ __launch_bounds__(256) void dct_k(const float* __restrict__ in,
                                             const float* __restrict__ sm, float* __restrict__ outf) {
  __shared__ float Cm[64];
  if (threadIdx.x < 64) Cm[threadIdx.x] = sm[OFF_C + threadIdx.x];
  __syncthreads();
  int pid = blockIdx.x * 256 + threadIdx.x;        // < 294912
  int wx = pid % 48;
  int t1 = pid / 48;
  int hy = t1 % 48; t1 /= 48;
  int ch = t1 & 63;
  int bb = t1 >> 6;
  const float* ip = in + (long)(bb * 64 + ch) * N_PIX + (hy * 8) * 384 + wx * 8;
  float X[8][8];
  #pragma unroll
  for (int r = 0; r < 8; r++) {
    float4 v0 = *reinterpret_cast<const float4*>(ip + r * 384);
    float4 v1 = *reinterpret_cast<const float4*>(ip + r * 384 + 4);
    X[r][0] = v0.x; X[r][1] = v0.y; X[r][2] = v0.z; X[r][3] = v0.w;
    X[r][4] = v1.x; X[r][5] = v1.y; X[r][6] = v1.z; X[r][7] = v1.w;
  }
  float T[8][8];
  #pragma unroll
  for (int a = 0; a < 8; a++)
    #pragma unroll
    for (int n = 0; n < 8; n++) {
      float s = 0.f;
      #pragma unroll
      for (int m = 0; m < 8; m++) s = fmaf(Cm[a * 8 + m], X[m][n], s);
      T[a][n] = s;
    }
  #pragma unroll
  for (int a = 0; a < 8; a++)
    #pragma unroll
    for (int b8 = 0; b8 < 8; b8++) {
      float s = 0.f;
      #pragma unroll
      for (int n = 0; n < 8; n++) s = fmaf(Cm[b8 * 8 + n], T[a][n], s);
      X[a][b8] = s;
    }
  float* op = outf + (long)(bb * 64 + ch) * L_LEN + (long)(hy * 48 + wx) * 64;
  float4* o4 = reinterpret_cast<float4*>(op);
  #pragma unroll
  for (int a = 0; a < 8; a++) {
    o4[a * 2]     = make_float4(X[a][0], X[a][1], X[a][2], X[a][3]);
    o4[a * 2 + 1] = make_float4(X[a][4], X[a][5], X[a][6], X[a][7]);
  }
}

// ---------------------------------------------------------------- Gram + norms
__global__ __launch_bounds__(256) void gram_k(const float* __restrict__ qf, const float* __restrict__ kf,
                                              float* __restrict__ sm) {
  int bh = blockIdx.y;              // bb*4 + h
  int bb = bh >> 2, h = bh & 3;
  int c = threadIdx.x >> 4, d = threadIdx.x & 15;
  long l0 = (long)blockIdx.x * 2304;
  const float4* q4 = reinterpret_cast<const float4*>(qf + ((long)bb * 64 + h * 16 + c) * L_LEN + l0);
  const float4* k4 = reinterpret_cast<const float4*>(kf + ((long)bb * 64 + h * 16 + d) * L_LEN + l0);
  float g = 0.f, nq = 0.f, nk = 0.f;
  for (int i = 0; i < 576; i++) {
    float4 a = q4[i], b = k4[i];
    g  = fmaf(a.x, b.x, g);  g  = fmaf(a.y, b.y, g);  g  = fmaf(a.z, b.z, g);  g  = fmaf(a.w, b.w, g);
    nq = fmaf(a.x, a.x, nq); nq = fmaf(a.y, a.y, nq); nq = fmaf(a.z, a.z, nq); nq = fmaf(a.w, a.w, nq);
    nk = fmaf(b.x, b.x, nk); nk = fmaf(b.y, b.y, nk); nk = fmaf(b.z, b.z, nk); nk = fmaf(b.w, b.w, nk);
  }
  atomicAdd(&sm[OFF_GRAM + bh * 256 + c * 16 + d], g);
  if (d == 0) atomicAdd(&sm[OFF_QQ + bh * 16 + c], nq);
  if (c == 0) atomicAdd(&sm[OFF_KK + bh * 16 + d], nk);
}

// ---------------------------------------------------------------- normalize + temperature + softmax over d
__global__ __launch_bounds__(256) void attn_k(const float* __restrict__ temp, float* __restrict__ sm) {
  int bh = blockIdx.x;
  int h = bh & 3;
  int t = threadIdx.x;
  int c = t >> 4, d = t & 15;
  float qn = fmaxf(sqrtf(sm[OFF_QQ + bh * 16 + c]), 1e-12f);
  float kn = fmaxf(sqrtf(sm[OFF_KK + bh * 16 + d]), 1e-12f);
  float v = sm[OFF_GRAM + bh * 256 + t] / (qn * kn) * temp[h];
  float mx = v;
  #pragma unroll
  for (int o = 8; o; o >>= 1) mx = fmaxf(mx, __shfl_xor(mx, o, 16));
  float e = expf(v - mx);
  float s = e;
  #pragma unroll
  for (int o = 8; o; o >>= 1) s += __shfl_xor(s, o, 16);
  sm[OFF_ATTN + bh * 256 + t] = e / s;
}

// ---------------------------------------------------------------- o = attn @ (q_fft*k_fft), in place over q_fft
__global__ __launch_bounds__(256) void combine_k(float* __restrict__ qf, const float* __restrict__ kf,
                                                 const float* __restrict__ sm) {
  __shared__ float A[256];
  int bh = blockIdx.y;
  A[threadIdx.x] = sm[OFF_ATTN + bh * 256 + threadIdx.x];
  __syncthreads();
  int bb = bh >> 2, h = bh & 3;
  long l = (long)blockIdx.x * 256 + threadIdx.x;
  float* qp = qf + ((long)bb * 64 + h * 16) * L_LEN + l;
  const float* kp = kf + ((long)bb * 64 + h * 16) * L_LEN + l;
  float p[16];
  #pragma unroll
  for (int d = 0; d < 16; d++) p[d] = qp[(long)d * L_LEN] * kp[(long)d * L_LEN];
  #pragma unroll
  for (int c = 0; c < 16; c++) {
    float s = 0.f;
    #pragma unroll
    for (int d = 0; d < 16; d++) s = fmaf(A[c * 16 + d], p[d], s);
    qp[(long)c * L_LEN] = s;
  }
}

// ---------------------------------------------------------------- IDCT: patch-flattened -> spatial
__global__ __launch_bounds__(256) void idct_k(const float* __restrict__ inf, const float* __restrict__ sm,
                                              float* __restrict__ out) {
  __shared__ float Ci[64];
  if (threadIdx.x < 64) Ci[threadIdx.x] = sm[OFF_CI + threadIdx.x];
  __syncthreads();
  int pid = blockIdx.x * 256 + threadIdx.x;
  int wx = pid % 48;
  int t1 = pid / 48;
  int hy = t1 % 48; t1 /= 48;
  int ch = t1 & 63;
  int bb = t1 >> 6;
  const float4* i4 = reinterpret_cast<const float4*>(inf + (long)(bb * 64 + ch) * L_LEN + (long)(hy * 48 + wx) * 64);
  float F[8][8];
  #pragma unroll
  for (int a = 0; a < 8; a++) {
    float4 v0 = i4[a * 2], v1 = i4[a * 2 + 1];
    F[a][0] = v0.x; F[a][1] = v0.y; F[a][2] = v0.z; F[a][3] = v0.w;
    F[a][4] = v1.x; F[a][5] = v1.y; F[a][6] = v1.z; F[a][7] = v1.w;
  }
  float T[8][8];
  #pragma unroll
  for (int m = 0; m < 8; m++)
    #pragma unroll
    for (int b8 = 0; b8 < 8; b8++) {
      float s = 0.f;
      #pragma unroll
      for (int a = 0; a < 8; a++) s = fmaf(Ci[m * 8 + a], F[a][b8], s);
      T[m][b8] = s;
    }
  #pragma unroll
  for (int m = 0; m < 8; m++)
    #pragma unroll
    for (int n = 0; n < 8; n++) {
      float s = 0.f;
      #pragma unroll
      for (int b8 = 0; b8 < 8; b8++) s = fmaf(Ci[n * 8 + b8], T[m][b8], s);
      F[m][n] = s;
    }
  float* op = out + (long)(bb * 64 + ch) * N_PIX + (hy * 8) * 384 + wx * 8;
  #pragma unroll
  for (int m = 0; m < 8; m++) {
    *reinterpret_cast<float4*>(op + m * 384)     = make_float4(F[m][0], F[m][1], F[m][2], F[m][3]);
    *reinterpret_cast<float4*>(op + m * 384 + 4) = make_float4(F[m][4], F[m][5], F[m][6], F[m][7]);
  }
}

// ---------------------------------------------------------------- u1 = prelu(dw3(q*out, w1a))
__global__ __launch_bounds__(256) void u1_k(const float* __restrict__ q, const float* __restrict__ om,
                                            const float* __restrict__ wa, const float* __restrict__ ap,
                                            float* __restrict__ u1) {
  int x = blockIdx.x * 64 + threadIdx.x;
  int y = blockIdx.y * 4 + threadIdx.y;
  int plane = blockIdx.z;
  int ch = plane & 63;
  float a1 = ap[0];
  const float* qp = q  + (long)plane * N_PIX;
  const float* op = om + (long)plane * N_PIX;
  const float* w1 = wa + ch * 9;
  float s1 = 0.f;
  #pragma unroll
  for (int dy = 0; dy < 3; dy++) {
    int yy = y + dy - 1;
    if ((unsigned)yy >= 384u) continue;
    #pragma unroll
    for (int dx = 0; dx < 3; dx++) {
      int xx = x + dx - 1;
      if ((unsigned)xx >= 384u) continue;
      int idx = yy * 384 + xx;
      s1 = fmaf(w1[dy * 3 + dx], qp[idx] * op[idx], s1);
    }
  }
  u1[(long)plane * N_PIX + y * 384 + x] = (s1 >= 0.f) ? s1 : a1 * s1;
}

// ---------------------------------------------------------------- u2 = prelu(dw3(v - lam*v*out, w2a))
__global__ __launch_bounds__(256) void u2_k(const float* __restrict__ v, const float* __restrict__ om,
                                            const float* __restrict__ wa, const float* __restrict__ ap,
                                            const float* __restrict__ sm, float* __restrict__ u2) {
  int x = blockIdx.x * 64 + threadIdx.x;
  int y = blockIdx.y * 4 + threadIdx.y;
  int plane = blockIdx.z;
  int ch = plane & 63;
  float a2 = ap[0];
  float lam = sm[OFF_LAM];
  const float* vp = v  + (long)plane * N_PIX;
  const float* op = om + (long)plane * N_PIX;
  const float* w2 = wa + ch * 9;
  float s2 = 0.f;
  #pragma unroll
  for (int dy = 0; dy < 3; dy++) {
    int yy = y + dy - 1;
    if ((unsigned)yy >= 384u) continue;
    #pragma unroll
    for (int dx = 0; dx < 3; dx++) {
      int xx = x + dx - 1;
      if ((unsigned)xx >= 384u) continue;
      int idx = yy * 384 + xx;
      float vv = vp[idx];
      s2 = fmaf(w2[dy * 3 + dx], vv - lam * (vv * op[idx]), s2);
    }
  }
  u2[(long)plane * N_PIX + y * 384 + x] = (s2 >= 0.f) ? s2 : a2 * s2;
}

// ---------------------------------------------------------------- outp = dw3(u1,w1b) + dw3(u2,w2b)
__global__ __launch_bounds__(256) void dw3dual_k(const float* __restrict__ u1, const float* __restrict__ u2,
                                                 const float* __restrict__ w1b, const float* __restrict__ w2b,
                                                 float* __restrict__ out) {
  int x = blockIdx.x * 64 + threadIdx.x;
  int y = blockIdx.y * 4 + threadIdx.y;
  int plane = blockIdx.z;
  int ch = plane & 63;
  const float* p1 = u1 + (long)plane * N_PIX;
  const float* p2 = u2 + (long)plane * N_PIX;
  const float* w1 = w1b + ch * 9;
  const float* w2 = w2b + ch * 9;
  float s = 0.f;
  #pragma unroll
  for (int dy = 0; dy < 3; dy++) {
    int yy = y + dy - 1;
    if ((unsigned)yy >= 384u) continue;
    #pragma unroll
    for (int dx = 0; dx < 3; dx++) {
      int xx = x + dx - 1;
      if ((unsigned)xx >= 384u) continue;
      int idx = yy * 384 + xx;
      s = fmaf(w1[dy * 3 + dx], p1[idx], s);
      s = fmaf(w2[dy * 3 + dx], p2[idx], s);
    }
  }
  out[(long)plane * N_PIX + y * 384 + x] = s;
}

// ---------------------------------------------------------------- launch
extern "C" void kernel_launch(void* const* d_in, const int* in_sizes, int n_in,
                              void* d_out, int out_size, void* d_ws, size_t ws_size,
                              hipStream_t stream) {
  const float* x            = (const float*)d_in[0];
  const float* nir          = (const float*)d_in[1];
  const float* w_hidden     = (const float*)d_in[2];
  const float* w_hidden_nir = (const float*)d_in[3];
  const float* w_dw         = (const float*)d_in[4];
  const float* w_dw_nir     = (const float*)d_in[5];
  const float* temperature  = (const float*)d_in[6];
  const float* w_proj_mid   = (const float*)d_in[7];
  const float* w_proj_out   = (const float*)d_in[8];
  const float* w_p1a        = (const float*)d_in[9];
  const float* a_p1         = (const float*)d_in[10];
  const float* w_p1b        = (const float*)d_in[11];
  const float* w_p2a        = (const float*)d_in[12];
  const float* a_p2         = (const float*)d_in[13];
  const float* w_p2b        = (const float*)d_in[14];
  const float* lq1          = (const float*)d_in[15];
  const float* lk1          = (const float*)d_in[16];
  const float* lq2          = (const float*)d_in[17];
  const float* lk2          = (const float*)d_in[18];

  float* OUT = (float*)d_out;
  float* W0 = (float*)d_ws;
  float* W1 = W0 + TENS_SZ;
  float* W2 = W1 + TENS_SZ;
  float* SM = W2 + TENS_SZ;        // small region

  size_t needed = (size_t)3 * TENS_SZ * sizeof(float) + 32768;
  if (ws_size < needed) {
    // sentinel: report ws budget through the absmax error (1000 + MB)
    diag_k<<<1, 1, 0, stream>>>(OUT, 1000.0f + (float)(ws_size >> 20));
    return;
  }

  dim3 blk256(256), blkDW(64, 4);
  dim3 gridDW(6, 96, NB * 64);

  init_k<<<1, 64, 0, stream>>>(lq1, lk1, lq2, lk2, SM);
  // hidden = conv1x1(x, w_hidden) -> W0 ; q = dw3(hidden, w_dw) -> OUT
  conv1x1_k<<<1152, blk256, 0, stream>>>(x, w_hidden, W0);
  dw3_k<<<gridDW, blkDW, 0, stream>>>(W0, w_dw, OUT);
  // k_pre = conv1x1(nir, w_hidden_nir[0:64]) -> W0 ; k = dw3 -> W1
  conv1x1_k<<<1152, blk256, 0, stream>>>(nir, w_hidden_nir, W0);
  dw3_k<<<gridDW, blkDW, 0, stream>>>(W0, w_dw_nir, W1);
  // v_pre = conv1x1(nir, w_hidden_nir[64:128]) -> W0 ; v = dw3 -> W2
  conv1x1_k<<<1152, blk256, 0, stream>>>(nir, w_hidden_nir + 64 * 64, W0);
  dw3_k<<<gridDW, blkDW, 0, stream>>>(W0, w_dw_nir + 64 * 9, W2);
  // k_fft = dct(k=W1) -> W0   (W1 free after)
  dct_k<<<1152, blk256, 0, stream>>>(W1, SM, W0);
  // q_fft = dct(q=OUT) -> W1
  dct_k<<<1152, blk256, 0, stream>>>(OUT, SM, W1);
  // Gram + norms + softmax
  gram_k<<<dim3(64, 8), blk256, 0, stream>>>(W1, W0, SM);
  attn_k<<<8, blk256, 0, stream>>>(temperature, SM);
  // o_freq = attn @ (q_fft*k_fft) in place on W1 ; idct -> W0 (spatial)
  combine_k<<<dim3(576, 8), blk256, 0, stream>>>(W1, W0, SM);
  idct_k<<<1152, blk256, 0, stream>>>(W1, SM, W0);
  // out = conv1x1(o, w_proj_mid) -> W1
  conv1x1_k<<<1152, blk256, 0, stream>>>(W0, w_proj_mid, W1);
  // u1 = prelu(dw3(q*out, w_p1a)) -> W0   (consumes q=OUT)
  u1_k<<<gridDW, blkDW, 0, stream>>>(OUT, W1, w_p1a, a_p1, W0);
  // u2 = prelu(dw3(v - lam*v*out, w_p2a)) -> OUT  (q dead, OUT reusable)
  u2_k<<<gridDW, blkDW, 0, stream>>>(W2, W1, w_p2a, a_p2, SM, OUT);
  // outp = dw3(u1,w_p1b) + dw3(u2,w_p2b) -> W1
  dw3dual_k<<<gridDW, blkDW, 0, stream>>>(W0, OUT, w_p1b, w_p2b, W1);
  // final = conv1x1(outp, w_proj_out) -> OUT
  conv1x1_k<<<1152, blk256, 0, stream>>>(W1, w_proj_out, OUT);
}

// Round 3
// 1521.604 us; speedup vs baseline: 1.0779x; 1.0779x over previous
//
#include <hip/hip_runtime.h>
#include <cmath>

#ifndef M_PI
#define M_PI 3.14159265358979323846
#endif

// Problem dims
#define NB      2
#define N_PIX   147456          // 384*384
#define L_LEN   147456
#define TENS_SZ ((long)NB * 64 * N_PIX)   // 18,874,368 floats per 64-plane tensor

// small-region float offsets (at d_ws + 3*TENS_SZ floats)
#define OFF_C    0      // C[a*8+m]
#define OFF_CI   64     // Ci[m*8+a]
#define OFF_LAM  128
#define OFF_GRAM 256    // [8][16][16]
#define OFF_QQ   2304   // [8][16]
#define OFF_KK   2432   // [8][16]
#define OFF_ATTN 2560   // [8][16][16]

// ---------------------------------------------------------------- init consts
__global__ __launch_bounds__(64) void init_k(const float* __restrict__ lq1, const float* __restrict__ lk1,
                                             const float* __restrict__ lq2, const float* __restrict__ lk2,
                                             float* __restrict__ sm) {
  int t = threadIdx.x;
  int a = t >> 3, m = t & 7;
  double cv = 2.0 * cos(M_PI * (double)((2 * m + 1) * a) / 16.0);
  sm[OFF_C + a * 8 + m] = (float)cv;
  sm[OFF_CI + m * 8 + a] = (float)(cv / ((a == 0) ? 32.0 : 16.0));
  float p1 = lq1[t] * lk1[t];
  float p2 = lq2[t] * lk2[t];
  #pragma unroll
  for (int off = 32; off; off >>= 1) {
    p1 += __shfl_xor(p1, off, 64);
    p2 += __shfl_xor(p2, off, 64);
  }
  if (t == 0) sm[OFF_LAM] = expf(p1) - expf(p2) + 0.70082066706704813f;
  for (int i = t; i < 2304; i += 64) sm[OFF_GRAM + i] = 0.f;
}

__global__ void diag_k(float* out, float v) { out[0] = v; }

// ---------------------------------------------------------------- conv1x1: 64->64, 256px x 64co tile, 8x8 reg blocking
// out[b, co, p] = sum_ci w[co*64+ci] * in[b, ci, p]
#define WS_P 68   // weight LDS row stride (floats); 68*4=272 B, 16B-aligned
#define IS_P 260  // input  LDS row stride (floats); 260*4=1040 B, 16B-aligned
__global__ __launch_bounds__(256) void conv1x1_k(const float* __restrict__ in, const float* __restrict__ w,
                                                 float* __restrict__ out) {
  __shared__ float ws[64 * WS_P];   // ws[ci][co]
  __shared__ float is[32 * IS_P];   // is[ci2][px]
  int t = threadIdx.x;
  // stage weights: global w[co*64+ci] contiguous reads, scatter to ws[ci][co]
  for (int j = t; j < 4096; j += 256) {
    int co = j >> 6, ci = j & 63;
    ws[ci * WS_P + co] = w[j];
  }
  long g = (long)blockIdx.x * 256;
  int bb = (int)(g / N_PIX);
  int p0 = (int)(g - (long)bb * N_PIX);
  const float* ip = in + (long)bb * 64 * N_PIX + p0;
  int tx = t & 31, ty = t >> 5;     // 32 px-threads (8 px each) x 8 co-threads (8 co each)
  float acc[8][8];
  #pragma unroll
  for (int i = 0; i < 8; i++)
    #pragma unroll
    for (int j = 0; j < 8; j++) acc[i][j] = 0.f;

  for (int cc = 0; cc < 2; cc++) {
    __syncthreads();                // protect previous is tile (and cover ws on first iter)
    // stage 32 ci rows x 256 px
    for (int j = t; j < 2048; j += 256) {    // 2048 float4 = 32 rows x 64 f4
      int row = j >> 6, c4 = j & 63;
      float4 v = *reinterpret_cast<const float4*>(ip + (long)(cc * 32 + row) * N_PIX + c4 * 4);
      *reinterpret_cast<float4*>(is + row * IS_P + c4 * 4) = v;
    }
    __syncthreads();
    #pragma unroll
    for (int ci2 = 0; ci2 < 32; ci2++) {
      int ci = cc * 32 + ci2;
      float4 a0 = *reinterpret_cast<const float4*>(is + ci2 * IS_P + tx * 8);
      float4 a1 = *reinterpret_cast<const float4*>(is + ci2 * IS_P + tx * 8 + 4);
      float4 b0 = *reinterpret_cast<const float4*>(ws + ci * WS_P + ty * 8);
      float4 b1 = *reinterpret_cast<const float4*>(ws + ci * WS_P + ty * 8 + 4);
      float av[8] = {a0.x, a0.y, a0.z, a0.w, a1.x, a1.y, a1.z, a1.w};
      float bv[8] = {b0.x, b0.y, b0.z, b0.w, b1.x, b1.y, b1.z, b1.w};
      #pragma unroll
      for (int pi = 0; pi < 8; pi++)
        #pragma unroll
        for (int cj = 0; cj < 8; cj++) acc[pi][cj] = fmaf(av[pi], bv[cj], acc[pi][cj]);
    }
  }
  float* op = out + (long)bb * 64 * N_PIX + p0;
  #pragma unroll
  for (int cj = 0; cj < 8; cj++) {
    int co = ty * 8 + cj;
    *reinterpret_cast<float4*>(op + (long)co * N_PIX + tx * 8) =
        make_float4(acc[0][cj], acc[1][cj], acc[2][cj], acc[3][cj]);
    *reinterpret_cast<float4*>(op + (long)co * N_PIX + tx * 8 + 4) =
        make_float4(acc[4][cj], acc[5][cj], acc[6][cj], acc[7][cj]);
  }
}

// ---------------------------------------------------------------- depthwise 3x3 (SAME, zero pad)
__global__ __launch_bounds__(256) void dw3_k(const float* __restrict__ in, const float* __restrict__ w,
                                             float* __restrict__ out) {
  int x = blockIdx.x * 64 + threadIdx.x;
  int y = blockIdx.y * 4 + threadIdx.y;
  int plane = blockIdx.z;
  int ch = plane & 63;
  const float* ip = in + (long)plane * N_PIX;
  const float* wp = w + ch * 9;
  float s = 0.f;
  #pragma unroll
  for (int dy = 0; dy < 3; dy++) {
    int yy = y + dy - 1;
    if ((unsigned)yy >= 384u) continue;
    #pragma unroll
    for (int dx = 0; dx < 3; dx++) {
      int xx = x + dx - 1;
      if ((unsigned)xx >= 384u) continue;
      s = fmaf(wp[dy * 3 + dx], ip[yy * 384 + xx], s);
    }
  }
  out[(long)plane * N_PIX + y * 384 + x] = s;
}

// ---------------------------------------------------------------- DCT: spatial -> patch-flattened
__global__ __launch_bounds__(256) void dct_k(const float* __restrict__ in,
                                             const float* __restrict__ sm, float* __restrict__ outf) {
  __shared__ float Cm[64];
  if (threadIdx.x < 64) Cm[threadIdx.x] = sm[OFF_C + threadIdx.x];
  __syncthreads();
  int pid = blockIdx.x * 256 + threadIdx.x;
  int wx = pid % 48;
  int t1 = pid / 48;
  int hy = t1 % 48; t1 /= 48;
  int ch = t1 & 63;
  int bb = t1 >> 6;
  const float* ip = in + (long)(bb * 64 + ch) * N_PIX + (hy * 8) * 384 + wx * 8;
  float X[8][8];
  #pragma unroll
  for (int r = 0; r < 8; r++) {
    float4 v0 = *reinterpret_cast<const float4*>(ip + r * 384);
    float4 v1 = *reinterpret_cast<const float4*>(ip + r * 384 + 4);
    X[r][0] = v0.x; X[r][1] = v0.y; X[r][2] = v0.z; X[r][3] = v0.w;
    X[r][4] = v1.x; X[r][5] = v1.y; X[r][6] = v1.z; X[r][7] = v1.w;
  }
  float T[8][8];
  #pragma unroll
  for (int a = 0; a < 8; a++)
    #pragma unroll
    for (int n = 0; n < 8; n++) {
      float s = 0.f;
      #pragma unroll
      for (int m = 0; m < 8; m++) s = fmaf(Cm[a * 8 + m], X[m][n], s);
      T[a][n] = s;
    }
  #pragma unroll
  for (int a = 0; a < 8; a++)
    #pragma unroll
    for (int b8 = 0; b8 < 8; b8++) {
      float s = 0.f;
      #pragma unroll
      for (int n = 0; n < 8; n++) s = fmaf(Cm[b8 * 8 + n], T[a][n], s);
      X[a][b8] = s;
    }
  float* op = outf + (long)(bb * 64 + ch) * L_LEN + (long)(hy * 48 + wx) * 64;
  float4* o4 = reinterpret_cast<float4*>(op);
  #pragma unroll
  for (int a = 0; a < 8; a++) {
    o4[a * 2]     = make_float4(X[a][0], X[a][1], X[a][2], X[a][3]);
    o4[a * 2 + 1] = make_float4(X[a][4], X[a][5], X[a][6], X[a][7]);
  }
}

// ---------------------------------------------------------------- Gram + norms, LDS-tiled (coalesced)
#define GS_P 132  // LDS row stride (floats); 132*4=528 B, 16B-aligned; 2-way bank alias only
__global__ __launch_bounds__(256) void gram_k(const float* __restrict__ qf, const float* __restrict__ kf,
                                              float* __restrict__ sm) {
  __shared__ float qs[16 * GS_P], ks[16 * GS_P];
  int t = threadIdx.x;
  int bh = blockIdx.y;              // bb*4 + h
  int bb = bh >> 2, h = bh & 3;
  const float* qbase = qf + ((long)bb * 64 + h * 16) * L_LEN;
  const float* kbase = kf + ((long)bb * 64 + h * 16) * L_LEN;
  int c = t >> 4, d = t & 15;
  long l0 = (long)blockIdx.x * 2048;
  float g = 0.f, nq = 0.f, nk = 0.f;
  for (int chunk = 0; chunk < 16; chunk++) {
    long lc = l0 + chunk * 128;
    __syncthreads();
    // stage 16 rows x 128 floats for q and k (coalesced float4)
    for (int j = t; j < 512; j += 256) {      // 512 f4 = 16 rows x 32 f4
      int row = j >> 5, c4 = j & 31;
      *reinterpret_cast<float4*>(qs + row * GS_P + c4 * 4) =
          *reinterpret_cast<const float4*>(qbase + (long)row * L_LEN + lc + c4 * 4);
      *reinterpret_cast<float4*>(ks + row * GS_P + c4 * 4) =
          *reinterpret_cast<const float4*>(kbase + (long)row * L_LEN + lc + c4 * 4);
    }
    __syncthreads();
    #pragma unroll
    for (int i = 0; i < 128; i += 4) {
      float4 a = *reinterpret_cast<const float4*>(qs + c * GS_P + i);
      float4 b = *reinterpret_cast<const float4*>(ks + d * GS_P + i);
      g  = fmaf(a.x, b.x, g);  g  = fmaf(a.y, b.y, g);  g  = fmaf(a.z, b.z, g);  g  = fmaf(a.w, b.w, g);
      nq = fmaf(a.x, a.x, nq); nq = fmaf(a.y, a.y, nq); nq = fmaf(a.z, a.z, nq); nq = fmaf(a.w, a.w, nq);
      nk = fmaf(b.x, b.x, nk); nk = fmaf(b.y, b.y, nk); nk = fmaf(b.z, b.z, nk); nk = fmaf(b.w, b.w, nk);
    }
  }
  atomicAdd(&sm[OFF_GRAM + bh * 256 + c * 16 + d], g);
  if (d == 0) atomicAdd(&sm[OFF_QQ + bh * 16 + c], nq);
  if (c == 0) atomicAdd(&sm[OFF_KK + bh * 16 + d], nk);
}

// ---------------------------------------------------------------- normalize + temperature + softmax over d
__global__ __launch_bounds__(256) void attn_k(const float* __restrict__ temp, float* __restrict__ sm) {
  int bh = blockIdx.x;
  int h = bh & 3;
  int t = threadIdx.x;
  int c = t >> 4, d = t & 15;
  float qn = fmaxf(sqrtf(sm[OFF_QQ + bh * 16 + c]), 1e-12f);
  float kn = fmaxf(sqrtf(sm[OFF_KK + bh * 16 + d]), 1e-12f);
  float v = sm[OFF_GRAM + bh * 256 + t] / (qn * kn) * temp[h];
  float mx = v;
  #pragma unroll
  for (int o = 8; o; o >>= 1) mx = fmaxf(mx, __shfl_xor(mx, o, 16));
  float e = expf(v - mx);
  float s = e;
  #pragma unroll
  for (int o = 8; o; o >>= 1) s += __shfl_xor(s, o, 16);
  sm[OFF_ATTN + bh * 256 + t] = e / s;
}

// ---------------------------------------------------------------- o = attn @ (q_fft*k_fft), in place over q_fft
__global__ __launch_bounds__(256) void combine_k(float* __restrict__ qf, const float* __restrict__ kf,
                                                 const float* __restrict__ sm) {
  __shared__ float A[256];
  int bh = blockIdx.y;
  A[threadIdx.x] = sm[OFF_ATTN + bh * 256 + threadIdx.x];
  __syncthreads();
  int bb = bh >> 2, h = bh & 3;
  long l = (long)blockIdx.x * 256 + threadIdx.x;
  float* qp = qf + ((long)bb * 64 + h * 16) * L_LEN + l;
  const float* kp = kf + ((long)bb * 64 + h * 16) * L_LEN + l;
  float p[16];
  #pragma unroll
  for (int d = 0; d < 16; d++) p[d] = qp[(long)d * L_LEN] * kp[(long)d * L_LEN];
  #pragma unroll
  for (int c = 0; c < 16; c++) {
    float s = 0.f;
    #pragma unroll
    for (int d = 0; d < 16; d++) s = fmaf(A[c * 16 + d], p[d], s);
    qp[(long)c * L_LEN] = s;
  }
}

// ---------------------------------------------------------------- IDCT
__global__ __launch_bounds__(256) void idct_k(const float* __restrict__ inf, const float* __restrict__ sm,
                                              float* __restrict__ out) {
  __shared__ float Ci[64];
  if (threadIdx.x < 64) Ci[threadIdx.x] = sm[OFF_CI + threadIdx.x];
  __syncthreads();
  int pid = blockIdx.x * 256 + threadIdx.x;
  int wx = pid % 48;
  int t1 = pid / 48;
  int hy = t1 % 48; t1 /= 48;
  int ch = t1 & 63;
  int bb = t1 >> 6;
  const float4* i4 = reinterpret_cast<const float4*>(inf + (long)(bb * 64 + ch) * L_LEN + (long)(hy * 48 + wx) * 64);
  float F[8][8];
  #pragma unroll
  for (int a = 0; a < 8; a++) {
    float4 v0 = i4[a * 2], v1 = i4[a * 2 + 1];
    F[a][0] = v0.x; F[a][1] = v0.y; F[a][2] = v0.z; F[a][3] = v0.w;
    F[a][4] = v1.x; F[a][5] = v1.y; F[a][6] = v1.z; F[a][7] = v1.w;
  }
  float T[8][8];
  #pragma unroll
  for (int m = 0; m < 8; m++)
    #pragma unroll
    for (int b8 = 0; b8 < 8; b8++) {
      float s = 0.f;
      #pragma unroll
      for (int a = 0; a < 8; a++) s = fmaf(Ci[m * 8 + a], F[a][b8], s);
      T[m][b8] = s;
    }
  #pragma unroll
  for (int m = 0; m < 8; m++)
    #pragma unroll
    for (int n = 0; n < 8; n++) {
      float s = 0.f;
      #pragma unroll
      for (int b8 = 0; b8 < 8; b8++) s = fmaf(Ci[n * 8 + b8], T[m][b8], s);
      F[m][n] = s;
    }
  float* op = out + (long)(bb * 64 + ch) * N_PIX + (hy * 8) * 384 + wx * 8;
  #pragma unroll
  for (int m = 0; m < 8; m++) {
    *reinterpret_cast<float4*>(op + m * 384)     = make_float4(F[m][0], F[m][1], F[m][2], F[m][3]);
    *reinterpret_cast<float4*>(op + m * 384 + 4) = make_float4(F[m][4], F[m][5], F[m][6], F[m][7]);
  }
}

// ---------------------------------------------------------------- u1 = prelu(dw3(q*out, w1a))
__global__ __launch_bounds__(256) void u1_k(const float* __restrict__ q, const float* __restrict__ om,
                                            const float* __restrict__ wa, const float* __restrict__ ap,
                                            float* __restrict__ u1) {
  int x = blockIdx.x * 64 + threadIdx.x;
  int y = blockIdx.y * 4 + threadIdx.y;
  int plane = blockIdx.z;
  int ch = plane & 63;
  float a1 = ap[0];
  const float* qp = q  + (long)plane * N_PIX;
  const float* op = om + (long)plane * N_PIX;
  const float* w1 = wa + ch * 9;
  float s1 = 0.f;
  #pragma unroll
  for (int dy = 0; dy < 3; dy++) {
    int yy = y + dy - 1;
    if ((unsigned)yy >= 384u) continue;
    #pragma unroll
    for (int dx = 0; dx < 3; dx++) {
      int xx = x + dx - 1;
      if ((unsigned)xx >= 384u) continue;
      int idx = yy * 384 + xx;
      s1 = fmaf(w1[dy * 3 + dx], qp[idx] * op[idx], s1);
    }
  }
  u1[(long)plane * N_PIX + y * 384 + x] = (s1 >= 0.f) ? s1 : a1 * s1;
}

// ---------------------------------------------------------------- u2 = prelu(dw3(v - lam*v*out, w2a))
__global__ __launch_bounds__(256) void u2_k(const float* __restrict__ v, const float* __restrict__ om,
                                            const float* __restrict__ wa, const float* __restrict__ ap,
                                            const float* __restrict__ sm, float* __restrict__ u2) {
  int x = blockIdx.x * 64 + threadIdx.x;
  int y = blockIdx.y * 4 + threadIdx.y;
  int plane = blockIdx.z;
  int ch = plane & 63;
  float a2 = ap[0];
  float lam = sm[OFF_LAM];
  const float* vp = v  + (long)plane * N_PIX;
  const float* op = om + (long)plane * N_PIX;
  const float* w2 = wa + ch * 9;
  float s2 = 0.f;
  #pragma unroll
  for (int dy = 0; dy < 3; dy++) {
    int yy = y + dy - 1;
    if ((unsigned)yy >= 384u) continue;
    #pragma unroll
    for (int dx = 0; dx < 3; dx++) {
      int xx = x + dx - 1;
      if ((unsigned)xx >= 384u) continue;
      int idx = yy * 384 + xx;
      float vv = vp[idx];
      s2 = fmaf(w2[dy * 3 + dx], vv - lam * (vv * op[idx]), s2);
    }
  }
  u2[(long)plane * N_PIX + y * 384 + x] = (s2 >= 0.f) ? s2 : a2 * s2;
}

// ---------------------------------------------------------------- outp = dw3(u1,w1b) + dw3(u2,w2b)
__global__ __launch_bounds__(256) void dw3dual_k(const float* __restrict__ u1, const float* __restrict__ u2,
                                                 const float* __restrict__ w1b, const float* __restrict__ w2b,
                                                 float* __restrict__ out) {
  int x = blockIdx.x * 64 + threadIdx.x;
  int y = blockIdx.y * 4 + threadIdx.y;
  int plane = blockIdx.z;
  int ch = plane & 63;
  const float* p1 = u1 + (long)plane * N_PIX;
  const float* p2 = u2 + (long)plane * N_PIX;
  const float* w1 = w1b + ch * 9;
  const float* w2 = w2b + ch * 9;
  float s = 0.f;
  #pragma unroll
  for (int dy = 0; dy < 3; dy++) {
    int yy = y + dy - 1;
    if ((unsigned)yy >= 384u) continue;
    #pragma unroll
    for (int dx = 0; dx < 3; dx++) {
      int xx = x + dx - 1;
      if ((unsigned)xx >= 384u) continue;
      int idx = yy * 384 + xx;
      s = fmaf(w1[dy * 3 + dx], p1[idx], s);
      s = fmaf(w2[dy * 3 + dx], p2[idx], s);
    }
  }
  out[(long)plane * N_PIX + y * 384 + x] = s;
}

// ---------------------------------------------------------------- launch
extern "C" void kernel_launch(void* const* d_in, const int* in_sizes, int n_in,
                              void* d_out, int out_size, void* d_ws, size_t ws_size,
                              hipStream_t stream) {
  const float* x            = (const float*)d_in[0];
  const float* nir          = (const float*)d_in[1];
  const float* w_hidden     = (const float*)d_in[2];
  const float* w_hidden_nir = (const float*)d_in[3];
  const float* w_dw         = (const float*)d_in[4];
  const float* w_dw_nir     = (const float*)d_in[5];
  const float* temperature  = (const float*)d_in[6];
  const float* w_proj_mid   = (const float*)d_in[7];
  const float* w_proj_out   = (const float*)d_in[8];
  const float* w_p1a        = (const float*)d_in[9];
  const float* a_p1         = (const float*)d_in[10];
  const float* w_p1b        = (const float*)d_in[11];
  const float* w_p2a        = (const float*)d_in[12];
  const float* a_p2         = (const float*)d_in[13];
  const float* w_p2b        = (const float*)d_in[14];
  const float* lq1          = (const float*)d_in[15];
  const float* lk1          = (const float*)d_in[16];
  const float* lq2          = (const float*)d_in[17];
  const float* lk2          = (const float*)d_in[18];

  float* OUT = (float*)d_out;
  float* W0 = (float*)d_ws;
  float* W1 = W0 + TENS_SZ;
  float* W2 = W1 + TENS_SZ;
  float* SM = W2 + TENS_SZ;

  size_t needed = (size_t)3 * TENS_SZ * sizeof(float) + 32768;
  if (ws_size < needed) {
    diag_k<<<1, 1, 0, stream>>>(OUT, 1000.0f + (float)(ws_size >> 20));
    return;
  }

  dim3 blk256(256), blkDW(64, 4);
  dim3 gridDW(6, 96, NB * 64);

  init_k<<<1, 64, 0, stream>>>(lq1, lk1, lq2, lk2, SM);
  // hidden = conv1x1(x, w_hidden) -> W0 ; q = dw3(hidden, w_dw) -> OUT
  conv1x1_k<<<1152, blk256, 0, stream>>>(x, w_hidden, W0);
  dw3_k<<<gridDW, blkDW, 0, stream>>>(W0, w_dw, OUT);
  // k_pre = conv1x1(nir, w_hidden_nir[0:64]) -> W0 ; k = dw3 -> W1
  conv1x1_k<<<1152, blk256, 0, stream>>>(nir, w_hidden_nir, W0);
  dw3_k<<<gridDW, blkDW, 0, stream>>>(W0, w_dw_nir, W1);
  // v_pre = conv1x1(nir, w_hidden_nir[64:128]) -> W0 ; v = dw3 -> W2
  conv1x1_k<<<1152, blk256, 0, stream>>>(nir, w_hidden_nir + 64 * 64, W0);
  dw3_k<<<gridDW, blkDW, 0, stream>>>(W0, w_dw_nir + 64 * 9, W2);
  // k_fft = dct(k=W1) -> W0   (W1 free after)
  dct_k<<<1152, blk256, 0, stream>>>(W1, SM, W0);
  // q_fft = dct(q=OUT) -> W1
  dct_k<<<1152, blk256, 0, stream>>>(OUT, SM, W1);
  // Gram + norms + softmax
  gram_k<<<dim3(72, 8), blk256, 0, stream>>>(W1, W0, SM);
  attn_k<<<8, blk256, 0, stream>>>(temperature, SM);
  // o_freq = attn @ (q_fft*k_fft) in place on W1 ; idct -> W0 (spatial)
  combine_k<<<dim3(576, 8), blk256, 0, stream>>>(W1, W0, SM);
  idct_k<<<1152, blk256, 0, stream>>>(W1, SM, W0);
  // out = conv1x1(o, w_proj_mid) -> W1
  conv1x1_k<<<1152, blk256, 0, stream>>>(W0, w_proj_mid, W1);
  // u1 = prelu(dw3(q*out, w_p1a)) -> W0   (consumes q=OUT)
  u1_k<<<gridDW, blkDW, 0, stream>>>(OUT, W1, w_p1a, a_p1, W0);
  // u2 = prelu(dw3(v - lam*v*out, w_p2a)) -> OUT
  u2_k<<<gridDW, blkDW, 0, stream>>>(W2, W1, w_p2a, a_p2, SM, OUT);
  // outp = dw3(u1,w_p1b) + dw3(u2,w_p2b) -> W1
  dw3dual_k<<<gridDW, blkDW, 0, stream>>>(W0, OUT, w_p1b, w_p2b, W1);
  // final = conv1x1(outp, w_proj_out) -> OUT
  conv1x1_k<<<1152, blk256, 0, stream>>>(W1, w_proj_out, OUT);
}

// Round 4
// 981.707 us; speedup vs baseline: 1.6707x; 1.5500x over previous
//
#include <hip/hip_runtime.h>
#include <cmath>

#ifndef M_PI
#define M_PI 3.14159265358979323846
#endif

// Problem dims
#define NB      2
#define N_PIX   147456          // 384*384
#define L_LEN   147456
#define TENS_SZ ((long)NB * 64 * N_PIX)   // floats per 64-plane tensor

// small-region float offsets (at d_ws + 3*TENS_SZ floats)
#define OFF_C    0
#define OFF_CI   64
#define OFF_LAM  128
#define OFF_GRAM 256
#define OFF_QQ   2304
#define OFF_KK   2432
#define OFF_ATTN 2560

// stencil tile geometry
#define TW 128
#define TH 16
#define LW 136   // TW + 8 (4-col halo both sides, float4-aligned)
#define LH 18    // TH + 2

// ---------------------------------------------------------------- init consts
__global__ __launch_bounds__(64) void init_k(const float* __restrict__ lq1, const float* __restrict__ lk1,
                                             const float* __restrict__ lq2, const float* __restrict__ lk2,
                                             float* __restrict__ sm) {
  int t = threadIdx.x;
  int a = t >> 3, m = t & 7;
  double cv = 2.0 * cos(M_PI * (double)((2 * m + 1) * a) / 16.0);
  sm[OFF_C + a * 8 + m] = (float)cv;
  sm[OFF_CI + m * 8 + a] = (float)(cv / ((a == 0) ? 32.0 : 16.0));
  float p1 = lq1[t] * lk1[t];
  float p2 = lq2[t] * lk2[t];
  #pragma unroll
  for (int off = 32; off; off >>= 1) {
    p1 += __shfl_xor(p1, off, 64);
    p2 += __shfl_xor(p2, off, 64);
  }
  if (t == 0) sm[OFF_LAM] = expf(p1) - expf(p2) + 0.70082066706704813f;
  for (int i = t; i < 2304; i += 64) sm[OFF_GRAM + i] = 0.f;
}

__global__ void diag_k(float* out, float v) { out[0] = v; }

// ---------------------------------------------------------------- conv1x1: 64->64, 256px x 64co tile, 8x8 reg blocking
#define WS_P 68
#define IS_P 260
__global__ __launch_bounds__(256) void conv1x1_k(const float* __restrict__ in, const float* __restrict__ w,
                                                 float* __restrict__ out) {
  __shared__ float ws[64 * WS_P];   // ws[ci][co]
  __shared__ float is[32 * IS_P];   // is[ci2][px]
  int t = threadIdx.x;
  for (int j = t; j < 4096; j += 256) {
    int co = j >> 6, ci = j & 63;
    ws[ci * WS_P + co] = w[j];
  }
  long g = (long)blockIdx.x * 256;
  int bb = (int)(g / N_PIX);
  int p0 = (int)(g - (long)bb * N_PIX);
  const float* ip = in + (long)bb * 64 * N_PIX + p0;
  int tx = t & 31, ty = t >> 5;
  float acc[8][8];
  #pragma unroll
  for (int i = 0; i < 8; i++)
    #pragma unroll
    for (int j = 0; j < 8; j++) acc[i][j] = 0.f;

  for (int cc = 0; cc < 2; cc++) {
    __syncthreads();
    for (int j = t; j < 2048; j += 256) {
      int row = j >> 6, c4 = j & 63;
      float4 v = *reinterpret_cast<const float4*>(ip + (long)(cc * 32 + row) * N_PIX + c4 * 4);
      *reinterpret_cast<float4*>(is + row * IS_P + c4 * 4) = v;
    }
    __syncthreads();
    #pragma unroll
    for (int ci2 = 0; ci2 < 32; ci2++) {
      int ci = cc * 32 + ci2;
      float4 a0 = *reinterpret_cast<const float4*>(is + ci2 * IS_P + tx * 8);
      float4 a1 = *reinterpret_cast<const float4*>(is + ci2 * IS_P + tx * 8 + 4);
      float4 b0 = *reinterpret_cast<const float4*>(ws + ci * WS_P + ty * 8);
      float4 b1 = *reinterpret_cast<const float4*>(ws + ci * WS_P + ty * 8 + 4);
      float av[8] = {a0.x, a0.y, a0.z, a0.w, a1.x, a1.y, a1.z, a1.w};
      float bv[8] = {b0.x, b0.y, b0.z, b0.w, b1.x, b1.y, b1.z, b1.w};
      #pragma unroll
      for (int pi = 0; pi < 8; pi++)
        #pragma unroll
        for (int cj = 0; cj < 8; cj++) acc[pi][cj] = fmaf(av[pi], bv[cj], acc[pi][cj]);
    }
  }
  float* op = out + (long)bb * 64 * N_PIX + p0;
  #pragma unroll
  for (int cj = 0; cj < 8; cj++) {
    int co = ty * 8 + cj;
    *reinterpret_cast<float4*>(op + (long)co * N_PIX + tx * 8) =
        make_float4(acc[0][cj], acc[1][cj], acc[2][cj], acc[3][cj]);
    *reinterpret_cast<float4*>(op + (long)co * N_PIX + tx * 8 + 4) =
        make_float4(acc[4][cj], acc[5][cj], acc[6][cj], acc[7][cj]);
  }
}

// ---------------------------------------------------------------- staging helper: guarded float4 tile load
__device__ __forceinline__ float4 load_g4(const float* __restrict__ p, int gy, int gx) {
  if ((unsigned)gy >= 384u) return make_float4(0.f, 0.f, 0.f, 0.f);
  if (gx >= 0 && gx + 3 < 384) return *reinterpret_cast<const float4*>(p + gy * 384 + gx);
  float e[4];
  #pragma unroll
  for (int i = 0; i < 4; i++) {
    int xx = gx + i;
    e[i] = ((unsigned)xx < 384u) ? p[gy * 384 + xx] : 0.f;
  }
  return make_float4(e[0], e[1], e[2], e[3]);
}

// ---------------------------------------------------------------- depthwise 3x3, LDS-tiled
__global__ __launch_bounds__(256) void dw3t_k(const float* __restrict__ in, const float* __restrict__ w,
                                              float* __restrict__ out) {
  __shared__ float sT[LH * LW];
  int plane = blockIdx.z;
  int ch = plane & 63;
  int x0 = blockIdx.x * TW, y0 = blockIdx.y * TH;
  const float* ip = in + (long)plane * N_PIX;
  int t = threadIdx.x;
  for (int j = t; j < LH * 34; j += 256) {
    int row = j / 34, c4 = j - row * 34;
    *reinterpret_cast<float4*>(sT + row * LW + c4 * 4) = load_g4(ip, y0 - 1 + row, x0 - 4 + c4 * 4);
  }
  __syncthreads();
  const float* wp = w + ch * 9;
  float w00 = wp[0], w01 = wp[1], w02 = wp[2];
  float w10 = wp[3], w11 = wp[4], w12 = wp[5];
  float w20 = wp[6], w21 = wp[7], w22 = wp[8];
  int col = t & 127, rg = t >> 7;
  int lc = col + 4;
  int r0 = rg * 8;
  float a0 = sT[r0 * LW + lc - 1],       a1 = sT[r0 * LW + lc],       a2 = sT[r0 * LW + lc + 1];
  float b0 = sT[(r0 + 1) * LW + lc - 1], b1 = sT[(r0 + 1) * LW + lc], b2 = sT[(r0 + 1) * LW + lc + 1];
  float* op = out + (long)plane * N_PIX + (long)(y0 + rg * 8) * 384 + x0 + col;
  #pragma unroll
  for (int i = 0; i < 8; i++) {
    int lr = r0 + i + 2;
    float c0 = sT[lr * LW + lc - 1], c1 = sT[lr * LW + lc], c2 = sT[lr * LW + lc + 1];
    float s = w00 * a0;
    s = fmaf(w01, a1, s); s = fmaf(w02, a2, s);
    s = fmaf(w10, b0, s); s = fmaf(w11, b1, s); s = fmaf(w12, b2, s);
    s = fmaf(w20, c0, s); s = fmaf(w21, c1, s); s = fmaf(w22, c2, s);
    op[i * 384] = s;
    a0 = b0; a1 = b1; a2 = b2;
    b0 = c0; b1 = c1; b2 = c2;
  }
}

// ---------------------------------------------------------------- fused u1/u2: stage p1=q*om, p2=v-lam*v*om, dual 3x3 + prelu
__global__ __launch_bounds__(256) void fuseu_k(const float* __restrict__ q, const float* __restrict__ om,
                                               const float* __restrict__ v,
                                               const float* __restrict__ w1a, const float* __restrict__ a1p,
                                               const float* __restrict__ w2a, const float* __restrict__ a2p,
                                               const float* __restrict__ sm,
                                               float* __restrict__ u1, float* __restrict__ u2) {
  __shared__ float s1[LH * LW], s2[LH * LW];
  int plane = blockIdx.z;
  int ch = plane & 63;
  int x0 = blockIdx.x * TW, y0 = blockIdx.y * TH;
  const float* qp = q  + (long)plane * N_PIX;
  const float* op = om + (long)plane * N_PIX;
  const float* vp = v  + (long)plane * N_PIX;
  float lam = sm[OFF_LAM];
  int t = threadIdx.x;
  for (int j = t; j < LH * 34; j += 256) {
    int row = j / 34, c4 = j - row * 34;
    int gy = y0 - 1 + row, gx = x0 - 4 + c4 * 4;
    float4 qv = load_g4(qp, gy, gx);
    float4 ov = load_g4(op, gy, gx);
    float4 vv = load_g4(vp, gy, gx);
    *reinterpret_cast<float4*>(s1 + row * LW + c4 * 4) =
        make_float4(qv.x * ov.x, qv.y * ov.y, qv.z * ov.z, qv.w * ov.w);
    *reinterpret_cast<float4*>(s2 + row * LW + c4 * 4) =
        make_float4(vv.x - lam * vv.x * ov.x, vv.y - lam * vv.y * ov.y,
                    vv.z - lam * vv.z * ov.z, vv.w - lam * vv.w * ov.w);
  }
  __syncthreads();
  const float* wp1 = w1a + ch * 9;
  const float* wp2 = w2a + ch * 9;
  float p00 = wp1[0], p01 = wp1[1], p02 = wp1[2], p10 = wp1[3], p11 = wp1[4], p12 = wp1[5], p20 = wp1[6], p21 = wp1[7], p22 = wp1[8];
  float q00 = wp2[0], q01 = wp2[1], q02 = wp2[2], q10 = wp2[3], q11 = wp2[4], q12 = wp2[5], q20 = wp2[6], q21 = wp2[7], q22 = wp2[8];
  float a1 = a1p[0], a2 = a2p[0];
  int col = t & 127, rg = t >> 7;
  int lc = col + 4;
  int r0 = rg * 8;
  float xa0 = s1[r0 * LW + lc - 1],       xa1 = s1[r0 * LW + lc],       xa2 = s1[r0 * LW + lc + 1];
  float xb0 = s1[(r0 + 1) * LW + lc - 1], xb1 = s1[(r0 + 1) * LW + lc], xb2 = s1[(r0 + 1) * LW + lc + 1];
  float ya0 = s2[r0 * LW + lc - 1],       ya1 = s2[r0 * LW + lc],       ya2 = s2[r0 * LW + lc + 1];
  float yb0 = s2[(r0 + 1) * LW + lc - 1], yb1 = s2[(r0 + 1) * LW + lc], yb2 = s2[(r0 + 1) * LW + lc + 1];
  long obase = (long)plane * N_PIX + (long)(y0 + rg * 8) * 384 + x0 + col;
  #pragma unroll
  for (int i = 0; i < 8; i++) {
    int lr = r0 + i + 2;
    float xc0 = s1[lr * LW + lc - 1], xc1 = s1[lr * LW + lc], xc2 = s1[lr * LW + lc + 1];
    float yc0 = s2[lr * LW + lc - 1], yc1 = s2[lr * LW + lc], yc2 = s2[lr * LW + lc + 1];
    float su = p00 * xa0;
    su = fmaf(p01, xa1, su); su = fmaf(p02, xa2, su);
    su = fmaf(p10, xb0, su); su = fmaf(p11, xb1, su); su = fmaf(p12, xb2, su);
    su = fmaf(p20, xc0, su); su = fmaf(p21, xc1, su); su = fmaf(p22, xc2, su);
    float sv = q00 * ya0;
    sv = fmaf(q01, ya1, sv); sv = fmaf(q02, ya2, sv);
    sv = fmaf(q10, yb0, sv); sv = fmaf(q11, yb1, sv); sv = fmaf(q12, yb2, sv);
    sv = fmaf(q20, yc0, sv); sv = fmaf(q21, yc1, sv); sv = fmaf(q22, yc2, sv);
    u1[obase + i * 384] = (su >= 0.f) ? su : a1 * su;
    u2[obase + i * 384] = (sv >= 0.f) ? sv : a2 * sv;
    xa0 = xb0; xa1 = xb1; xa2 = xb2; xb0 = xc0; xb1 = xc1; xb2 = xc2;
    ya0 = yb0; ya1 = yb1; ya2 = yb2; yb0 = yc0; yb1 = yc1; yb2 = yc2;
  }
}

// ---------------------------------------------------------------- dual depthwise: out = dw3(u1,w1b)+dw3(u2,w2b), LDS-tiled
__global__ __launch_bounds__(256) void dw3dual_k(const float* __restrict__ u1, const float* __restrict__ u2,
                                                 const float* __restrict__ w1b, const float* __restrict__ w2b,
                                                 float* __restrict__ out) {
  __shared__ float s1[LH * LW], s2[LH * LW];
  int plane = blockIdx.z;
  int ch = plane & 63;
  int x0 = blockIdx.x * TW, y0 = blockIdx.y * TH;
  const float* p1 = u1 + (long)plane * N_PIX;
  const float* p2 = u2 + (long)plane * N_PIX;
  int t = threadIdx.x;
  for (int j = t; j < LH * 34; j += 256) {
    int row = j / 34, c4 = j - row * 34;
    int gy = y0 - 1 + row, gx = x0 - 4 + c4 * 4;
    *reinterpret_cast<float4*>(s1 + row * LW + c4 * 4) = load_g4(p1, gy, gx);
    *reinterpret_cast<float4*>(s2 + row * LW + c4 * 4) = load_g4(p2, gy, gx);
  }
  __syncthreads();
  const float* wp1 = w1b + ch * 9;
  const float* wp2 = w2b + ch * 9;
  float p00 = wp1[0], p01 = wp1[1], p02 = wp1[2], p10 = wp1[3], p11 = wp1[4], p12 = wp1[5], p20 = wp1[6], p21 = wp1[7], p22 = wp1[8];
  float q00 = wp2[0], q01 = wp2[1], q02 = wp2[2], q10 = wp2[3], q11 = wp2[4], q12 = wp2[5], q20 = wp2[6], q21 = wp2[7], q22 = wp2[8];
  int col = t & 127, rg = t >> 7;
  int lc = col + 4;
  int r0 = rg * 8;
  float xa0 = s1[r0 * LW + lc - 1],       xa1 = s1[r0 * LW + lc],       xa2 = s1[r0 * LW + lc + 1];
  float xb0 = s1[(r0 + 1) * LW + lc - 1], xb1 = s1[(r0 + 1) * LW + lc], xb2 = s1[(r0 + 1) * LW + lc + 1];
  float ya0 = s2[r0 * LW + lc - 1],       ya1 = s2[r0 * LW + lc],       ya2 = s2[r0 * LW + lc + 1];
  float yb0 = s2[(r0 + 1) * LW + lc - 1], yb1 = s2[(r0 + 1) * LW + lc], yb2 = s2[(r0 + 1) * LW + lc + 1];
  float* op = out + (long)plane * N_PIX + (long)(y0 + rg * 8) * 384 + x0 + col;
  #pragma unroll
  for (int i = 0; i < 8; i++) {
    int lr = r0 + i + 2;
    float xc0 = s1[lr * LW + lc - 1], xc1 = s1[lr * LW + lc], xc2 = s1[lr * LW + lc + 1];
    float yc0 = s2[lr * LW + lc - 1], yc1 = s2[lr * LW + lc], yc2 = s2[lr * LW + lc + 1];
    float s = p00 * xa0;
    s = fmaf(p01, xa1, s); s = fmaf(p02, xa2, s);
    s = fmaf(p10, xb0, s); s = fmaf(p11, xb1, s); s = fmaf(p12, xb2, s);
    s = fmaf(p20, xc0, s); s = fmaf(p21, xc1, s); s = fmaf(p22, xc2, s);
    s = fmaf(q00, ya0, s); s = fmaf(q01, ya1, s); s = fmaf(q02, ya2, s);
    s = fmaf(q10, yb0, s); s = fmaf(q11, yb1, s); s = fmaf(q12, yb2, s);
    s = fmaf(q20, yc0, s); s = fmaf(q21, yc1, s); s = fmaf(q22, yc2, s);
    op[i * 384] = s;
    xa0 = xb0; xa1 = xb1; xa2 = xb2; xb0 = xc0; xb1 = xc1; xb2 = xc2;
    ya0 = yb0; ya1 = yb1; ya2 = yb2; yb0 = yc0; yb1 = yc1; yb2 = yc2;
  }
}

// ---------------------------------------------------------------- DCT: spatial -> patch-flattened
__global__ __launch_bounds__(256) void dct_k(const float* __restrict__ in,
                                             const float* __restrict__ sm, float* __restrict__ outf) {
  __shared__ float Cm[64];
  if (threadIdx.x < 64) Cm[threadIdx.x] = sm[OFF_C + threadIdx.x];
  __syncthreads();
  int pid = blockIdx.x * 256 + threadIdx.x;
  int wx = pid % 48;
  int t1 = pid / 48;
  int hy = t1 % 48; t1 /= 48;
  int ch = t1 & 63;
  int bb = t1 >> 6;
  const float* ip = in + (long)(bb * 64 + ch) * N_PIX + (hy * 8) * 384 + wx * 8;
  float X[8][8];
  #pragma unroll
  for (int r = 0; r < 8; r++) {
    float4 v0 = *reinterpret_cast<const float4*>(ip + r * 384);
    float4 v1 = *reinterpret_cast<const float4*>(ip + r * 384 + 4);
    X[r][0] = v0.x; X[r][1] = v0.y; X[r][2] = v0.z; X[r][3] = v0.w;
    X[r][4] = v1.x; X[r][5] = v1.y; X[r][6] = v1.z; X[r][7] = v1.w;
  }
  float T[8][8];
  #pragma unroll
  for (int a = 0; a < 8; a++)
    #pragma unroll
    for (int n = 0; n < 8; n++) {
      float s = 0.f;
      #pragma unroll
      for (int m = 0; m < 8; m++) s = fmaf(Cm[a * 8 + m], X[m][n], s);
      T[a][n] = s;
    }
  #pragma unroll
  for (int a = 0; a < 8; a++)
    #pragma unroll
    for (int b8 = 0; b8 < 8; b8++) {
      float s = 0.f;
      #pragma unroll
      for (int n = 0; n < 8; n++) s = fmaf(Cm[b8 * 8 + n], T[a][n], s);
      X[a][b8] = s;
    }
  float* op = outf + (long)(bb * 64 + ch) * L_LEN + (long)(hy * 48 + wx) * 64;
  float4* o4 = reinterpret_cast<float4*>(op);
  #pragma unroll
  for (int a = 0; a < 8; a++) {
    o4[a * 2]     = make_float4(X[a][0], X[a][1], X[a][2], X[a][3]);
    o4[a * 2 + 1] = make_float4(X[a][4], X[a][5], X[a][6], X[a][7]);
  }
}

// ---------------------------------------------------------------- Gram + norms, LDS-tiled
#define GS_P 132
__global__ __launch_bounds__(256) void gram_k(const float* __restrict__ qf, const float* __restrict__ kf,
                                              float* __restrict__ sm) {
  __shared__ float qs[16 * GS_P], ks[16 * GS_P];
  int t = threadIdx.x;
  int bh = blockIdx.y;
  int bb = bh >> 2, h = bh & 3;
  const float* qbase = qf + ((long)bb * 64 + h * 16) * L_LEN;
  const float* kbase = kf + ((long)bb * 64 + h * 16) * L_LEN;
  int c = t >> 4, d = t & 15;
  long l0 = (long)blockIdx.x * 2048;
  float g = 0.f, nq = 0.f, nk = 0.f;
  for (int chunk = 0; chunk < 16; chunk++) {
    long lc = l0 + chunk * 128;
    __syncthreads();
    for (int j = t; j < 512; j += 256) {
      int row = j >> 5, c4 = j & 31;
      *reinterpret_cast<float4*>(qs + row * GS_P + c4 * 4) =
          *reinterpret_cast<const float4*>(qbase + (long)row * L_LEN + lc + c4 * 4);
      *reinterpret_cast<float4*>(ks + row * GS_P + c4 * 4) =
          *reinterpret_cast<const float4*>(kbase + (long)row * L_LEN + lc + c4 * 4);
    }
    __syncthreads();
    #pragma unroll
    for (int i = 0; i < 128; i += 4) {
      float4 a = *reinterpret_cast<const float4*>(qs + c * GS_P + i);
      float4 b = *reinterpret_cast<const float4*>(ks + d * GS_P + i);
      g  = fmaf(a.x, b.x, g);  g  = fmaf(a.y, b.y, g);  g  = fmaf(a.z, b.z, g);  g  = fmaf(a.w, b.w, g);
      nq = fmaf(a.x, a.x, nq); nq = fmaf(a.y, a.y, nq); nq = fmaf(a.z, a.z, nq); nq = fmaf(a.w, a.w, nq);
      nk = fmaf(b.x, b.x, nk); nk = fmaf(b.y, b.y, nk); nk = fmaf(b.z, b.z, nk); nk = fmaf(b.w, b.w, nk);
    }
  }
  atomicAdd(&sm[OFF_GRAM + bh * 256 + c * 16 + d], g);
  if (d == 0) atomicAdd(&sm[OFF_QQ + bh * 16 + c], nq);
  if (c == 0) atomicAdd(&sm[OFF_KK + bh * 16 + d], nk);
}

// ---------------------------------------------------------------- normalize + temperature + softmax over d
__global__ __launch_bounds__(256) void attn_k(const float* __restrict__ temp, float* __restrict__ sm) {
  int bh = blockIdx.x;
  int h = bh & 3;
  int t = threadIdx.x;
  int c = t >> 4, d = t & 15;
  float qn = fmaxf(sqrtf(sm[OFF_QQ + bh * 16 + c]), 1e-12f);
  float kn = fmaxf(sqrtf(sm[OFF_KK + bh * 16 + d]), 1e-12f);
  float v = sm[OFF_GRAM + bh * 256 + t] / (qn * kn) * temp[h];
  float mx = v;
  #pragma unroll
  for (int o = 8; o; o >>= 1) mx = fmaxf(mx, __shfl_xor(mx, o, 16));
  float e = expf(v - mx);
  float s = e;
  #pragma unroll
  for (int o = 8; o; o >>= 1) s += __shfl_xor(s, o, 16);
  sm[OFF_ATTN + bh * 256 + t] = e / s;
}

// ---------------------------------------------------------------- o = attn @ (q_fft*k_fft), in place over q_fft
__global__ __launch_bounds__(256) void combine_k(float* __restrict__ qf, const float* __restrict__ kf,
                                                 const float* __restrict__ sm) {
  __shared__ float A[256];
  int bh = blockIdx.y;
  A[threadIdx.x] = sm[OFF_ATTN + bh * 256 + threadIdx.x];
  __syncthreads();
  int bb = bh >> 2, h = bh & 3;
  long l = (long)blockIdx.x * 256 + threadIdx.x;
  float* qp = qf + ((long)bb * 64 + h * 16) * L_LEN + l;
  const float* kp = kf + ((long)bb * 64 + h * 16) * L_LEN + l;
  float p[16];
  #pragma unroll
  for (int d = 0; d < 16; d++) p[d] = qp[(long)d * L_LEN] * kp[(long)d * L_LEN];
  #pragma unroll
  for (int c = 0; c < 16; c++) {
    float s = 0.f;
    #pragma unroll
    for (int d = 0; d < 16; d++) s = fmaf(A[c * 16 + d], p[d], s);
    qp[(long)c * L_LEN] = s;
  }
}

// ---------------------------------------------------------------- IDCT
__global__ __launch_bounds__(256) void idct_k(const float* __restrict__ inf, const float* __restrict__ sm,
                                              float* __restrict__ out) {
  __shared__ float Ci[64];
  if (threadIdx.x < 64) Ci[threadIdx.x] = sm[OFF_CI + threadIdx.x];
  __syncthreads();
  int pid = blockIdx.x * 256 + threadIdx.x;
  int wx = pid % 48;
  int t1 = pid / 48;
  int hy = t1 % 48; t1 /= 48;
  int ch = t1 & 63;
  int bb = t1 >> 6;
  const float4* i4 = reinterpret_cast<const float4*>(inf + (long)(bb * 64 + ch) * L_LEN + (long)(hy * 48 + wx) * 64);
  float F[8][8];
  #pragma unroll
  for (int a = 0; a < 8; a++) {
    float4 v0 = i4[a * 2], v1 = i4[a * 2 + 1];
    F[a][0] = v0.x; F[a][1] = v0.y; F[a][2] = v0.z; F[a][3] = v0.w;
    F[a][4] = v1.x; F[a][5] = v1.y; F[a][6] = v1.z; F[a][7] = v1.w;
  }
  float T[8][8];
  #pragma unroll
  for (int m = 0; m < 8; m++)
    #pragma unroll
    for (int b8 = 0; b8 < 8; b8++) {
      float s = 0.f;
      #pragma unroll
      for (int a = 0; a < 8; a++) s = fmaf(Ci[m * 8 + a], F[a][b8], s);
      T[m][b8] = s;
    }
  #pragma unroll
  for (int m = 0; m < 8; m++)
    #pragma unroll
    for (int n = 0; n < 8; n++) {
      float s = 0.f;
      #pragma unroll
      for (int b8 = 0; b8 < 8; b8++) s = fmaf(Ci[n * 8 + b8], T[m][b8], s);
      F[m][n] = s;
    }
  float* op = out + (long)(bb * 64 + ch) * N_PIX + (hy * 8) * 384 + wx * 8;
  #pragma unroll
  for (int m = 0; m < 8; m++) {
    *reinterpret_cast<float4*>(op + m * 384)     = make_float4(F[m][0], F[m][1], F[m][2], F[m][3]);
    *reinterpret_cast<float4*>(op + m * 384 + 4) = make_float4(F[m][4], F[m][5], F[m][6], F[m][7]);
  }
}

// ---------------------------------------------------------------- launch
extern "C" void kernel_launch(void* const* d_in, const int* in_sizes, int n_in,
                              void* d_out, int out_size, void* d_ws, size_t ws_size,
                              hipStream_t stream) {
  const float* x            = (const float*)d_in[0];
  const float* nir          = (const float*)d_in[1];
  const float* w_hidden     = (const float*)d_in[2];
  const float* w_hidden_nir = (const float*)d_in[3];
  const float* w_dw         = (const float*)d_in[4];
  const float* w_dw_nir     = (const float*)d_in[5];
  const float* temperature  = (const float*)d_in[6];
  const float* w_proj_mid   = (const float*)d_in[7];
  const float* w_proj_out   = (const float*)d_in[8];
  const float* w_p1a        = (const float*)d_in[9];
  const float* a_p1         = (const float*)d_in[10];
  const float* w_p1b        = (const float*)d_in[11];
  const float* w_p2a        = (const float*)d_in[12];
  const float* a_p2         = (const float*)d_in[13];
  const float* w_p2b        = (const float*)d_in[14];
  const float* lq1          = (const float*)d_in[15];
  const float* lk1          = (const float*)d_in[16];
  const float* lq2          = (const float*)d_in[17];
  const float* lk2          = (const float*)d_in[18];

  float* OUT = (float*)d_out;
  float* W0 = (float*)d_ws;
  float* W1 = W0 + TENS_SZ;
  float* W2 = W1 + TENS_SZ;
  float* SM = W2 + TENS_SZ;

  size_t needed = (size_t)3 * TENS_SZ * sizeof(float) + 32768;
  if (ws_size < needed) {
    diag_k<<<1, 1, 0, stream>>>(OUT, 1000.0f + (float)(ws_size >> 20));
    return;
  }

  dim3 blk256(256);
  dim3 gridST(3, 24, NB * 64);     // stencil tiles: 128x16 over 384x384, 128 planes

  init_k<<<1, 64, 0, stream>>>(lq1, lk1, lq2, lk2, SM);
  // hidden = conv1x1(x, w_hidden) -> W0 ; q = dw3(hidden, w_dw) -> OUT
  conv1x1_k<<<1152, blk256, 0, stream>>>(x, w_hidden, W0);
  dw3t_k<<<gridST, blk256, 0, stream>>>(W0, w_dw, OUT);
  // k_pre = conv1x1(nir, w_hidden_nir[0:64]) -> W0 ; k = dw3 -> W1
  conv1x1_k<<<1152, blk256, 0, stream>>>(nir, w_hidden_nir, W0);
  dw3t_k<<<gridST, blk256, 0, stream>>>(W0, w_dw_nir, W1);
  // v_pre = conv1x1(nir, w_hidden_nir[64:128]) -> W0 ; v = dw3 -> W2
  conv1x1_k<<<1152, blk256, 0, stream>>>(nir, w_hidden_nir + 64 * 64, W0);
  dw3t_k<<<gridST, blk256, 0, stream>>>(W0, w_dw_nir + 64 * 9, W2);
  // k_fft = dct(k=W1) -> W0
  dct_k<<<1152, blk256, 0, stream>>>(W1, SM, W0);
  // q_fft = dct(q=OUT) -> W1
  dct_k<<<1152, blk256, 0, stream>>>(OUT, SM, W1);
  // Gram + norms + softmax
  gram_k<<<dim3(72, 8), blk256, 0, stream>>>(W1, W0, SM);
  attn_k<<<8, blk256, 0, stream>>>(temperature, SM);
  // o_freq = attn @ (q_fft*k_fft) in place on W1 ; idct -> W0 (spatial)
  combine_k<<<dim3(576, 8), blk256, 0, stream>>>(W1, W0, SM);
  idct_k<<<1152, blk256, 0, stream>>>(W1, SM, W0);
  // out = conv1x1(o, w_proj_mid) -> W1
  conv1x1_k<<<1152, blk256, 0, stream>>>(W0, w_proj_mid, W1);
  // u1 -> W0, u2 -> OUT (fused; consumes q=OUT, om=W1, v=W2)
  fuseu_k<<<gridST, blk256, 0, stream>>>(OUT, W1, W2, w_p1a, a_p1, w_p2a, a_p2, SM, W0, OUT);
  // outp = dw3(u1,w_p1b) + dw3(u2,w_p2b) -> W1
  dw3dual_k<<<gridST, blk256, 0, stream>>>(W0, OUT, w_p1b, w_p2b, W1);
  // final = conv1x1(outp, w_proj_out) -> OUT
  conv1x1_k<<<1152, blk256, 0, stream>>>(W1, w_proj_out, OUT);
}